// Round 5
// baseline (210.001 us; speedup 1.0000x reference)
//
#include <hip/hip_runtime.h>
#include <hip/hip_bf16.h>

#define NT 4096   // tokens
#define CD 768    // channels
#define NH 12     // heads
#define HD 64     // head dim
#define CQ 2304   // 3*CD

typedef __bf16 bf;
typedef __bf16 v8bf __attribute__((ext_vector_type(8)));
typedef __bf16 v4bf __attribute__((ext_vector_type(4)));
typedef float  v4f  __attribute__((ext_vector_type(4)));

// async global->LDS, 16B per lane; LDS dest is wave-uniform base + lane*16
__device__ __forceinline__ void gld16(const bf* g, bf* l) {
  __builtin_amdgcn_global_load_lds(
      (__attribute__((address_space(1))) void*)g,
      (__attribute__((address_space(3))) void*)l,
      16, 0, 0);
}

__device__ __forceinline__ float fexp2(float x) {
#if defined(__HIP_DEVICE_COMPILE__)
  return __builtin_amdgcn_exp2f(x);
#else
  return x;  // host pass never executes device code
#endif
}

// ---------- merged prep: fp32->bf16 cast of x  +  transpose-cast of both weights ----------
__global__ __launch_bounds__(256) void prep(
    const float* __restrict__ x, const float* __restrict__ wqkv,
    const float* __restrict__ wproj, bf* __restrict__ Xb,
    bf* __restrict__ WqkvT, bf* __restrict__ WpT) {
  __shared__ float tile[32][33];
  const int b = blockIdx.x, tid = threadIdx.x;
  if (b < 3072) {
    const int i = b * 256 + tid;  // n4 = 786432 = 3072*256 exactly
    const float4 v = ((const float4*)x)[i];
    bf o4[4] = {(bf)v.x, (bf)v.y, (bf)v.z, (bf)v.w};
    ((ushort4*)Xb)[i] = *(const ushort4*)o4;
    return;
  }
  const float* in;
  bf* out;
  int rows, cols, c0, r0;
  if (b < 4800) {
    const int t = b - 3072;           // 72 col-blocks x 24 row-blocks
    in = wqkv; out = WqkvT; rows = CD; cols = CQ;
    c0 = (t % 72) * 32; r0 = (t / 72) * 32;
  } else {
    const int t = b - 4800;           // 24 x 24
    in = wproj; out = WpT; rows = CD; cols = CD;
    c0 = (t % 24) * 32; r0 = (t / 24) * 32;
  }
  const int tx = tid & 31, ty = tid >> 5;  // 32 x 8
#pragma unroll
  for (int j = 0; j < 32; j += 8)
    tile[ty + j][tx] = in[(size_t)(r0 + ty + j) * cols + (c0 + tx)];
  __syncthreads();
#pragma unroll
  for (int j = 0; j < 32; j += 8)
    out[(size_t)(c0 + ty + j) * rows + (r0 + tx)] = (bf)tile[tx][ty + j];
}

// ------------- QKV GEMM: Xb[4096x768] * WqkvT[2304x768]^T -------------
// BK=64 single-buffered (m97 pattern: stage -> vmcnt0 -> barrier -> compute -> barrier),
// 12 K-iterations, 32 MFMA per wave per iter. XOR swizzle (u^(r&7)) on staging source
// and fragment reads kills the 128B-stride bank conflicts.
// V is written TRANSPOSED with the per-32-key PV slot permutation baked in.
__global__ __launch_bounds__(256, 3) void gemm_qkv(
    const bf* __restrict__ A, const bf* __restrict__ Bt,
    bf* __restrict__ Qb, bf* __restrict__ Kb, bf* __restrict__ Vtb) {
  __shared__ __align__(16) bf As[128 * 64];   // 16 KB
  __shared__ __align__(16) bf Bs[128 * 64];   // 16 KB
  const int tid = threadIdx.x;
  const int lane = tid & 63, wave = tid >> 6;
  const int lane15 = lane & 15, quad = lane >> 4;
  const int waveM = wave & 1, waveN = wave >> 1;
  const int bm = blockIdx.x * 128;
  const int bn = blockIdx.y * 128;

  v4f acc[4][4];
#pragma unroll
  for (int i = 0; i < 4; ++i)
#pragma unroll
    for (int j = 0; j < 4; ++j) acc[i][j] = (v4f){0.f, 0.f, 0.f, 0.f};

  for (int k0 = 0; k0 < CD; k0 += 64) {
    // stage 128x64 A and B tiles, source-side XOR swizzle: unit u of row r holds
    // global dims ((u^(r&7))*8 ..+8)
#pragma unroll
    for (int p = 0; p < 4; ++p) {
      const int t = tid + p * 256;
      const int r = t >> 3, u = t & 7;
      gld16(A + (size_t)(bm + r) * CD + k0 + ((u ^ (r & 7)) << 3), As + t * 8);
    }
#pragma unroll
    for (int p = 0; p < 4; ++p) {
      const int t = tid + p * 256;
      const int r = t >> 3, u = t & 7;
      gld16(Bt + (size_t)(bn + r) * CD + k0 + ((u ^ (r & 7)) << 3), Bs + t * 8);
    }
    asm volatile("s_waitcnt vmcnt(0)" ::: "memory");
    __syncthreads();

    v8bf af[4][2], bfr[4][2];
#pragma unroll
    for (int mt = 0; mt < 4; ++mt) {
      const int rr = waveM * 64 + mt * 16 + lane15;
      const int r7 = rr & 7;
      af[mt][0] = *(const v8bf*)(As + rr * 64 + ((quad ^ r7) << 3));
      af[mt][1] = *(const v8bf*)(As + rr * 64 + (((quad ^ 4) ^ r7) << 3));
    }
#pragma unroll
    for (int nt = 0; nt < 4; ++nt) {
      const int rr = waveN * 64 + nt * 16 + lane15;
      const int r7 = rr & 7;
      bfr[nt][0] = *(const v8bf*)(Bs + rr * 64 + ((quad ^ r7) << 3));
      bfr[nt][1] = *(const v8bf*)(Bs + rr * 64 + (((quad ^ 4) ^ r7) << 3));
    }
#pragma unroll
    for (int mt = 0; mt < 4; ++mt)
#pragma unroll
      for (int nt = 0; nt < 4; ++nt) {
        acc[mt][nt] = __builtin_amdgcn_mfma_f32_16x16x32_bf16(af[mt][0], bfr[nt][0], acc[mt][nt], 0, 0, 0);
        acc[mt][nt] = __builtin_amdgcn_mfma_f32_16x16x32_bf16(af[mt][1], bfr[nt][1], acc[mt][nt], 0, 0, 0);
      }
    __syncthreads();
  }

  const float QSCALE = 0.125f * 1.4426950408889634f;  // fold D^-0.5 * log2(e)
#pragma unroll
  for (int mt = 0; mt < 4; ++mt) {
    const int rowB = bm + waveM * 64 + mt * 16 + quad * 4;
#pragma unroll
    for (int nt = 0; nt < 4; ++nt) {
      const int col = bn + waveN * 64 + nt * 16 + lane15;
      const int s = col / CD;
      const int rem = col - s * CD;
      const int h = rem >> 6, d = rem & 63;
      if (s == 2) {
        // 4 consecutive keys -> one 8B store at the PV-permuted position
        bf vp[4];
#pragma unroll
        for (int i = 0; i < 4; ++i) vp[i] = (bf)acc[mt][nt][i];
        const int pos = (rowB & ~31) + (((rowB & 15) >> 2) << 3) + (((rowB >> 4) & 1) << 2);
        *(uint2*)(Vtb + ((size_t)h * HD + d) * NT + pos) = *(const uint2*)vp;
      } else {
#pragma unroll
        for (int i = 0; i < 4; ++i) {
          const float v = acc[mt][nt][i];
          const int row = rowB + i;
          if (s == 0) Qb[((size_t)h * NT + row) * HD + d] = (bf)(v * QSCALE);
          else        Kb[((size_t)h * NT + row) * HD + d] = (bf)v;
        }
      }
    }
  }
}

// ------------- attention: block = 1 head x 64 Q rows, 256 threads. -------------
// R5: K moved from LDS to REGISTERS. R4 counters showed the LDS pipe was the busiest
// resource (12 waves x 8 ds_read_b128 x ~12cy = 46% of the iteration) and the K ds_read
// sat at the head of the serial chain (barrier -> ds_read -> lgkm -> QK MFMA). The K
// A-fragment needs no swizzle from global: lane reads K[kh*32+e*16+lane15][quad*8(+32)]
// as two dwordx4. kA/kB double-buffered in regs, prefetched one tile ahead, drained by
// the existing end-of-iter vmcnt(0). Removes 4/8 ds_reads, half the LDS staging writes,
// and the loop-head lgkm wait. K is L2-resident (head-XCD affinity) so the 2x read
// redundancy (sh=0/1 waves share keys) stays on-chip. LDS: 32KB -> 16.6KB (V only).
// Loop unrolled x2 so kA/kB indexing is compile-time (no scratch). Keeps: den-via-
// ones-MFMA, direct P pack into A-fragment, setprio, vmcnt(0)+barrier per iter.
__global__ __launch_bounds__(256, 3) void attn(
    const bf* __restrict__ Qb, const bf* __restrict__ Kb,
    const bf* __restrict__ Vtb, bf* __restrict__ Ob) {
  // [V0 8K][V1 8K][Ls 256B]; epilogue reuses 0..16K as 4 x 4KB Red regions.
  __shared__ __align__(16) char smem[16640];

  // head->XCD affinity: blocks of one head land on one XCD (b%8 round-robin heuristic)
  const int b = blockIdx.x;
  int h, qt;
  if (b < 512) { h = b & 7;        qt = b >> 3; }
  else { const int bb = b - 512; h = 8 + (bb & 3); qt = bb >> 2; }
  const int q0 = qt * 64;

  const int tid = threadIdx.x;
  const int wave = tid >> 6, lane = tid & 63;
  const int kh = wave & 1;      // key half (32 keys) of the 64-key tile
  const int sh = wave >> 1;     // Q-subtile half: subs {sh*2, sh*2+1}
  const int lane15 = lane & 15, quad = lane >> 4;

  const bf* Kh = Kb + (size_t)h * NT * HD;
  const bf* Vh = Vtb + (size_t)h * HD * NT;

  // Q fragments for this wave's 2 sub-tiles (B-operand: n=lane15=Q row, k=quad*8+j)
  v8bf aQ[2][2];
#pragma unroll
  for (int sl = 0; sl < 2; ++sl) {
    const int qrow = q0 + (sh * 2 + sl) * 16 + lane15;
    aQ[sl][0] = *(const v8bf*)(Qb + ((size_t)h * NT + qrow) * HD + quad * 8);
    aQ[sl][1] = *(const v8bf*)(Qb + ((size_t)h * NT + qrow) * HD + 32 + quad * 8);
  }

  v4f o[2][4];
#pragma unroll
  for (int sl = 0; sl < 2; ++sl)
#pragma unroll
    for (int dt = 0; dt < 4; ++dt) o[sl][dt] = (v4f){0.f, 0.f, 0.f, 0.f};
  v4f den[2] = {(v4f){0.f, 0.f, 0.f, 0.f}, (v4f){0.f, 0.f, 0.f, 0.f}};
  v8bf vone;
#pragma unroll
  for (int i = 0; i < 8; ++i) vone[i] = (bf)1.0f;

  // per-lane K base pointers (e=0/1 rows); advance by kt*HD per tile
  const bf* Kl0 = Kh + (size_t)(kh * 32 + lane15) * HD + quad * 8;
  const bf* Kl1 = Kh + (size_t)(kh * 32 + 16 + lane15) * HD + quad * 8;

  // load this wave's K fragments for tile kt into a named reg set (compile-time idx)
  auto loadK = [&](v8bf (&kr)[2][2], int kt) {
    const bf* p0 = Kl0 + (size_t)kt * HD;
    const bf* p1 = Kl1 + (size_t)kt * HD;
    kr[0][0] = *(const v8bf*)(p0);
    kr[0][1] = *(const v8bf*)(p0 + 32);
    kr[1][0] = *(const v8bf*)(p1);
    kr[1][1] = *(const v8bf*)(p1 + 32);
  };

  // stage 64-key V tile kt into buffer half `half`: 8KB, 2 gld16/thread.
  auto stageV = [&](int half, int kt) {
    bf* Vdst = (bf*)(smem + half * 8192);
#pragma unroll
    for (int p = 0; p < 2; ++p) {
      const int L = p * 256 + tid;      // 512 units = 64 d-rows x 8 units
      const int d = L >> 3, u = L & 7;
      gld16(Vh + (size_t)d * NT + kt + ((u ^ (d & 7)) << 3), Vdst + L * 8);
    }
  };

  auto computeT = [&](int half, v8bf (&kr)[2][2]) {
    const bf* Vbuf = (const bf*)(smem + half * 8192);
    // S^T = K Q^T on this wave's 32 keys x its 2 Q sub-tiles; P = exp2(S) straight
    // into the v8bf A-fragment.
    v8bf aP8[2];
#pragma unroll
    for (int e = 0; e < 2; ++e) {
#pragma unroll
      for (int sl = 0; sl < 2; ++sl) {
        v4f z = (v4f){0.f, 0.f, 0.f, 0.f};
        __builtin_amdgcn_s_setprio(1);
        z = __builtin_amdgcn_mfma_f32_16x16x32_bf16(kr[e][0], aQ[sl][0], z, 0, 0, 0);
        z = __builtin_amdgcn_mfma_f32_16x16x32_bf16(kr[e][1], aQ[sl][1], z, 0, 0, 0);
        __builtin_amdgcn_s_setprio(0);
#pragma unroll
        for (int r = 0; r < 4; ++r) aP8[sl][e * 4 + r] = (bf)fexp2(z[r]);
      }
    }
    // denominator via ones-column MFMA, then O += P V on this wave's 32 keys.
#pragma unroll
    for (int sl = 0; sl < 2; ++sl)
      den[sl] = __builtin_amdgcn_mfma_f32_16x16x32_bf16(aP8[sl], vone, den[sl], 0, 0, 0);
#pragma unroll
    for (int dt = 0; dt < 4; ++dt) {
      const int d = dt * 16 + lane15;
      const v8bf bv = *(const v8bf*)(Vbuf + d * 64 + (((kh * 4 + quad) ^ (d & 7)) << 3));
      __builtin_amdgcn_s_setprio(1);
#pragma unroll
      for (int sl = 0; sl < 2; ++sl)
        o[sl][dt] = __builtin_amdgcn_mfma_f32_16x16x32_bf16(aP8[sl], bv, o[sl][dt], 0, 0, 0);
      __builtin_amdgcn_s_setprio(0);
    }
  };

  v8bf kA[2][2], kB[2][2];
  loadK(kA, 0);
  stageV(0, 0);
  asm volatile("s_waitcnt vmcnt(0)" ::: "memory");
  __syncthreads();

#pragma unroll 1
  for (int it2 = 0; it2 < 32; ++it2) {
    const int it = it2 * 2;
    // body A (half 0, uses kA; prefetches tile it+1 into V1 + kB)
    stageV(1, (it + 1) * 64);
    loadK(kB, (it + 1) * 64);
    computeT(0, kA);
    asm volatile("s_waitcnt vmcnt(0)" ::: "memory");
    __syncthreads();
    // body B (half 1, uses kB; prefetches tile it+2 into V0 + kA)
    if (it + 2 < 64) {
      stageV(0, (it + 2) * 64);
      loadK(kA, (it + 2) * 64);
    }
    computeT(1, kB);
    asm volatile("s_waitcnt vmcnt(0)" ::: "memory");
    __syncthreads();
  }

  // cross-wave combine: waves {sh*2, sh*2+1} (kh=0,1) hold key-half partials of the
  // same 2 subs. Two phases (one per local sub); each wave finalizes 2 of the 4 dt.
  float* Red = (float*)smem;             // 4 regions x 1024 f = 16KB
  float* Ls  = (float*)(smem + 16384);   // 64 f
#pragma unroll
  for (int sl = 0; sl < 2; ++sl) {
    __syncthreads();
    float* reg = Red + wave * 1024;
#pragma unroll
    for (int dt = 0; dt < 4; ++dt)
      *(v4f*)(reg + dt * 256 + lane15 * 16 + quad * 4) = o[sl][dt];
    if (lane15 == 0) {
#pragma unroll
      for (int i = 0; i < 4; ++i) Ls[wave * 16 + quad * 4 + i] = den[sl][i];
    }
    __syncthreads();
    const int s = sh * 2 + sl;
    const float dsum = Ls[(sh * 2) * 16 + lane15] + Ls[(sh * 2 + 1) * 16 + lane15];
    const float linv = 1.f / dsum;
#pragma unroll
    for (int dh = 0; dh < 2; ++dh) {
      const int dt = kh * 2 + dh;
      v4f sum = *(const v4f*)(Red + (sh * 2) * 1024 + dt * 256 + lane15 * 16 + quad * 4);
      sum     += *(const v4f*)(Red + (sh * 2 + 1) * 1024 + dt * 256 + lane15 * 16 + quad * 4);
#pragma unroll
      for (int i = 0; i < 4; ++i) {
        const float linv_i = __shfl(linv, quad * 4 + i, 64);
        const int row = q0 + s * 16 + quad * 4 + i;
        Ob[(size_t)row * CD + h * HD + dt * 16 + lane15] = (bf)(sum[i] * linv_i);
      }
    }
  }
}

// ------------- proj GEMM: Ob[4096x768] * WpT[768x768]^T + bias, 64x128 tiles ----------------
__global__ __launch_bounds__(256, 4) void gemm_proj(
    const bf* __restrict__ A, const bf* __restrict__ Bt,
    const float* __restrict__ bias, float* __restrict__ out) {
  __shared__ __align__(16) bf As[2][64 * 32];
  __shared__ __align__(16) bf Bs[2][128 * 32];
  const int tid = threadIdx.x;
  const int lane = tid & 63, wave = tid >> 6;
  const int lane15 = lane & 15, quad = lane >> 4;
  const int bm = blockIdx.x * 64;
  const int bn = blockIdx.y * 128;

  v4f acc[4][2];
#pragma unroll
  for (int i = 0; i < 4; ++i)
#pragma unroll
    for (int j = 0; j < 2; ++j) acc[i][j] = (v4f){0.f, 0.f, 0.f, 0.f};

  auto stageG = [&](int half, int k0) {
    {
      const int r = tid >> 2, c = (tid & 3) * 8;
      gld16(A + (size_t)(bm + r) * CD + k0 + c, As[half] + tid * 8);
    }
#pragma unroll
    for (int p = 0; p < 2; ++p) {
      const int t = tid + p * 256;
      const int r = t >> 2, c = (t & 3) * 8;
      gld16(Bt + (size_t)(bn + r) * CD + k0 + c, Bs[half] + t * 8);
    }
  };

  stageG(0, 0);
  asm volatile("s_waitcnt vmcnt(0)" ::: "memory");
  __syncthreads();

  for (int it = 0; it < CD / 32; ++it) {
    const int half = it & 1;
    if (it + 1 < CD / 32) stageG(half ^ 1, (it + 1) * 32);

    v8bf af[4], bfr[2];
#pragma unroll
    for (int mt = 0; mt < 4; ++mt)
      af[mt] = *(const v8bf*)(As[half] + (mt * 16 + lane15) * 32 + quad * 8);
#pragma unroll
    for (int nt = 0; nt < 2; ++nt)
      bfr[nt] = *(const v8bf*)(Bs[half] + (wave * 32 + nt * 16 + lane15) * 32 + quad * 8);
#pragma unroll
    for (int mt = 0; mt < 4; ++mt)
#pragma unroll
      for (int nt = 0; nt < 2; ++nt)
        acc[mt][nt] = __builtin_amdgcn_mfma_f32_16x16x32_bf16(af[mt], bfr[nt], acc[mt][nt], 0, 0, 0);

    asm volatile("s_waitcnt vmcnt(0)" ::: "memory");
    __syncthreads();
  }

#pragma unroll
  for (int mt = 0; mt < 4; ++mt) {
    const int rowB = bm + mt * 16 + quad * 4;
#pragma unroll
    for (int nt = 0; nt < 2; ++nt) {
      const int col = bn + wave * 32 + nt * 16 + lane15;
      const float bcol = bias[col];
#pragma unroll
      for (int i = 0; i < 4; ++i)
        out[(size_t)(rowB + i) * CD + col] = acc[mt][nt][i] + bcol;
    }
  }
}

extern "C" void kernel_launch(void* const* d_in, const int* in_sizes, int n_in,
                              void* d_out, int out_size, void* d_ws, size_t ws_size,
                              hipStream_t stream) {
  const float* x     = (const float*)d_in[0];   // [4096][768] fp32
  const float* wqkv  = (const float*)d_in[1];   // [768][2304] fp32
  const float* wproj = (const float*)d_in[2];   // [768][768]  fp32
  const float* bproj = (const float*)d_in[3];   // [768]       fp32
  float* out = (float*)d_out;                   // [4096][768] fp32

  bf* ws    = (bf*)d_ws;
  bf* Xb    = ws;  ws += (size_t)NT * CD;        // [4096][768] bf16
  bf* WqkvT = ws;  ws += (size_t)CQ * CD;        // [2304][768]
  bf* WpT   = ws;  ws += (size_t)CD * CD;        // [768][768]
  bf* Qb    = ws;  ws += (size_t)NH * NT * HD;   // [h][n][d], pre-scaled by 0.125*log2e
  bf* Kb    = ws;  ws += (size_t)NH * NT * HD;   // [h][n][d]
  bf* Vtb   = ws;  ws += (size_t)NH * NT * HD;   // [h][d][n], keys PV-slot-permuted per 32
  bf* Ob    = ws;  ws += (size_t)NT * CD;        // [n][h*64+d]

  prep<<<5376, 256, 0, stream>>>(x, wqkv, wproj, Xb, WqkvT, WpT);
  gemm_qkv<<<dim3(NT / 128, CQ / 128), 256, 0, stream>>>(Xb, WqkvT, Qb, Kb, Vtb);
  attn<<<768, 256, 0, stream>>>(Qb, Kb, Vtb, Ob);
  gemm_proj<<<dim3(NT / 64, CD / 128), 256, 0, stream>>>(Ob, WpT, bproj, out);
}

// Round 6
// 164.258 us; speedup vs baseline: 1.2785x; 1.2785x over previous
//
#include <hip/hip_runtime.h>
#include <hip/hip_bf16.h>

#define NT 4096   // tokens
#define CD 768    // channels
#define NH 12     // heads
#define HD 64     // head dim
#define CQ 2304   // 3*CD

typedef __bf16 bf;
typedef __bf16 v8bf __attribute__((ext_vector_type(8)));
typedef __bf16 v4bf __attribute__((ext_vector_type(4)));
typedef float  v4f  __attribute__((ext_vector_type(4)));

// async global->LDS, 16B per lane; LDS dest is wave-uniform base + lane*16
__device__ __forceinline__ void gld16(const bf* g, bf* l) {
  __builtin_amdgcn_global_load_lds(
      (__attribute__((address_space(1))) void*)g,
      (__attribute__((address_space(3))) void*)l,
      16, 0, 0);
}

__device__ __forceinline__ float fexp2(float x) {
#if defined(__HIP_DEVICE_COMPILE__)
  return __builtin_amdgcn_exp2f(x);
#else
  return x;  // host pass never executes device code
#endif
}

// ---------- merged prep: fp32->bf16 cast of x  +  transpose-cast of both weights ----------
__global__ __launch_bounds__(256) void prep(
    const float* __restrict__ x, const float* __restrict__ wqkv,
    const float* __restrict__ wproj, bf* __restrict__ Xb,
    bf* __restrict__ WqkvT, bf* __restrict__ WpT) {
  __shared__ float tile[32][33];
  const int b = blockIdx.x, tid = threadIdx.x;
  if (b < 3072) {
    const int i = b * 256 + tid;  // n4 = 786432 = 3072*256 exactly
    const float4 v = ((const float4*)x)[i];
    bf o4[4] = {(bf)v.x, (bf)v.y, (bf)v.z, (bf)v.w};
    ((ushort4*)Xb)[i] = *(const ushort4*)o4;
    return;
  }
  const float* in;
  bf* out;
  int rows, cols, c0, r0;
  if (b < 4800) {
    const int t = b - 3072;           // 72 col-blocks x 24 row-blocks
    in = wqkv; out = WqkvT; rows = CD; cols = CQ;
    c0 = (t % 72) * 32; r0 = (t / 72) * 32;
  } else {
    const int t = b - 4800;           // 24 x 24
    in = wproj; out = WpT; rows = CD; cols = CD;
    c0 = (t % 24) * 32; r0 = (t / 24) * 32;
  }
  const int tx = tid & 31, ty = tid >> 5;  // 32 x 8
#pragma unroll
  for (int j = 0; j < 32; j += 8)
    tile[ty + j][tx] = in[(size_t)(r0 + ty + j) * cols + (c0 + tx)];
  __syncthreads();
#pragma unroll
  for (int j = 0; j < 32; j += 8)
    out[(size_t)(c0 + ty + j) * rows + (r0 + tx)] = (bf)tile[tx][ty + j];
}

// ------------- QKV GEMM: Xb[4096x768] * WqkvT[2304x768]^T -------------
// R6: 128x96 tiles (was 128x128). CQ/96 = 24 -> grid 32x24 = 768 blocks = exactly
// 3 blocks/CU (was 576 = 2.25/CU: the 3-block CUs ran 1.33x longer than 2-block CUs,
// ~11% idle). CD%96==0 so a 96-col tile never straddles the Q/K/V boundary: s = by>>3
// is BLOCK-UNIFORM -> no per-element col/CD division, no divergent epilogue branch.
// BK=64 single-buffered m97 pattern; XOR swizzle unchanged; V written transposed with
// the per-32-key PV slot permutation baked in (depends only on rowB - unchanged).
__global__ __launch_bounds__(256, 3) void gemm_qkv(
    const bf* __restrict__ A, const bf* __restrict__ Bt,
    bf* __restrict__ Qb, bf* __restrict__ Kb, bf* __restrict__ Vtb) {
  __shared__ __align__(16) bf As[128 * 64];   // 16 KB
  __shared__ __align__(16) bf Bs[96 * 64];    // 12 KB
  const int tid = threadIdx.x;
  const int lane = tid & 63, wave = tid >> 6;
  const int lane15 = lane & 15, quad = lane >> 4;
  const int waveM = wave & 1, waveN = wave >> 1;
  const int bm = blockIdx.x * 128;
  const int by = blockIdx.y;            // 96-col tile index, 0..23
  const int bn = by * 96;

  v4f acc[4][3];
#pragma unroll
  for (int i = 0; i < 4; ++i)
#pragma unroll
    for (int j = 0; j < 3; ++j) acc[i][j] = (v4f){0.f, 0.f, 0.f, 0.f};

  for (int k0 = 0; k0 < CD; k0 += 64) {
    // stage 128x64 A tile (1024 units) and 96x64 B tile (768 units), src-side XOR swizzle
#pragma unroll
    for (int p = 0; p < 4; ++p) {
      const int t = tid + p * 256;
      const int r = t >> 3, u = t & 7;
      gld16(A + (size_t)(bm + r) * CD + k0 + ((u ^ (r & 7)) << 3), As + t * 8);
    }
#pragma unroll
    for (int p = 0; p < 3; ++p) {
      const int t = tid + p * 256;
      const int r = t >> 3, u = t & 7;
      gld16(Bt + (size_t)(bn + r) * CD + k0 + ((u ^ (r & 7)) << 3), Bs + t * 8);
    }
    asm volatile("s_waitcnt vmcnt(0)" ::: "memory");
    __syncthreads();

    v8bf af[4][2], bfr[3][2];
#pragma unroll
    for (int mt = 0; mt < 4; ++mt) {
      const int rr = waveM * 64 + mt * 16 + lane15;
      const int r7 = rr & 7;
      af[mt][0] = *(const v8bf*)(As + rr * 64 + ((quad ^ r7) << 3));
      af[mt][1] = *(const v8bf*)(As + rr * 64 + (((quad ^ 4) ^ r7) << 3));
    }
#pragma unroll
    for (int nt = 0; nt < 3; ++nt) {
      const int rr = waveN * 48 + nt * 16 + lane15;
      const int r7 = rr & 7;
      bfr[nt][0] = *(const v8bf*)(Bs + rr * 64 + ((quad ^ r7) << 3));
      bfr[nt][1] = *(const v8bf*)(Bs + rr * 64 + (((quad ^ 4) ^ r7) << 3));
    }
#pragma unroll
    for (int mt = 0; mt < 4; ++mt)
#pragma unroll
      for (int nt = 0; nt < 3; ++nt) {
        acc[mt][nt] = __builtin_amdgcn_mfma_f32_16x16x32_bf16(af[mt][0], bfr[nt][0], acc[mt][nt], 0, 0, 0);
        acc[mt][nt] = __builtin_amdgcn_mfma_f32_16x16x32_bf16(af[mt][1], bfr[nt][1], acc[mt][nt], 0, 0, 0);
      }
    __syncthreads();
  }

  const float QSCALE = 0.125f * 1.4426950408889634f;  // fold D^-0.5 * log2(e)
  const int s = by >> 3;                // block-uniform: 0=Q 1=K 2=V
#pragma unroll
  for (int mt = 0; mt < 4; ++mt) {
    const int rowB = bm + waveM * 64 + mt * 16 + quad * 4;
#pragma unroll
    for (int nt = 0; nt < 3; ++nt) {
      const int rem = (by & 7) * 96 + waveN * 48 + nt * 16 + lane15;  // 0..767
      const int h = rem >> 6, d = rem & 63;
      if (s == 2) {
        // 4 consecutive keys -> one 8B store at the PV-permuted position
        bf vp[4];
#pragma unroll
        for (int i = 0; i < 4; ++i) vp[i] = (bf)acc[mt][nt][i];
        const int pos = (rowB & ~31) + (((rowB & 15) >> 2) << 3) + (((rowB >> 4) & 1) << 2);
        *(uint2*)(Vtb + ((size_t)h * HD + d) * NT + pos) = *(const uint2*)vp;
      } else {
#pragma unroll
        for (int i = 0; i < 4; ++i) {
          const float v = acc[mt][nt][i];
          const int row = rowB + i;
          if (s == 0) Qb[((size_t)h * NT + row) * HD + d] = (bf)(v * QSCALE);
          else        Kb[((size_t)h * NT + row) * HD + d] = (bf)v;
        }
      }
    }
  }
}

// ------------- attention: block = 1 head x 64 Q rows, 256 threads. -------------
// R6: R4 structure restored (K back in LDS -- R5's per-lane global K gather was a
// TA/L1 cacheline-request bottleneck: 16 lines touched per load inst, Mfma/VALU both
// halved). New vs R4: main loop unrolled x2 with COMPILE-TIME buffer halves, so all
// 8 ds_read addresses + 4 DMA dests are loop-invariant and hoisted (was ~8-16 VALU/
// wave-iter of half-toggle address math; VALUBusy 42.5% was the top pipe).
// launch_bounds (256,3) not (256,4): hoisted addrs need headroom above a 64-VGPR cap.
// Keeps: den-via-ones-MFMA, direct P pack into A-fragment, setprio, vmcnt(0)+barrier.
__global__ __launch_bounds__(256, 3) void attn(
    const bf* __restrict__ Qb, const bf* __restrict__ Kb,
    const bf* __restrict__ Vtb, bf* __restrict__ Ob) {
  // [K0 8K][V0 8K][K1 8K][V1 8K]; epilogue reuses 0..16K as 4 x 4KB regions,
  // 16384.. as the denominator scratch.
  __shared__ __align__(16) char smem[32768];

  // head->XCD affinity: blocks of one head land on one XCD (b%8 round-robin heuristic)
  const int b = blockIdx.x;
  int h, qt;
  if (b < 512) { h = b & 7;        qt = b >> 3; }
  else { const int bb = b - 512; h = 8 + (bb & 3); qt = bb >> 2; }
  const int q0 = qt * 64;

  const int tid = threadIdx.x;
  const int wave = tid >> 6, lane = tid & 63;
  const int kh = wave & 1;      // key half (32 keys) of the 64-key tile
  const int sh = wave >> 1;     // Q-subtile half: subs {sh*2, sh*2+1}
  const int lane15 = lane & 15, quad = lane >> 4;

  const bf* Kh = Kb + (size_t)h * NT * HD;
  const bf* Vh = Vtb + (size_t)h * HD * NT;

  // Q fragments for this wave's 2 sub-tiles (B-operand: n=lane15=Q row, k=quad*8+j)
  v8bf aQ[2][2];
#pragma unroll
  for (int sl = 0; sl < 2; ++sl) {
    const int qrow = q0 + (sh * 2 + sl) * 16 + lane15;
    aQ[sl][0] = *(const v8bf*)(Qb + ((size_t)h * NT + qrow) * HD + quad * 8);
    aQ[sl][1] = *(const v8bf*)(Qb + ((size_t)h * NT + qrow) * HD + 32 + quad * 8);
  }

  v4f o[2][4];
#pragma unroll
  for (int sl = 0; sl < 2; ++sl)
#pragma unroll
    for (int dt = 0; dt < 4; ++dt) o[sl][dt] = (v4f){0.f, 0.f, 0.f, 0.f};
  v4f den[2] = {(v4f){0.f, 0.f, 0.f, 0.f}, (v4f){0.f, 0.f, 0.f, 0.f}};
  v8bf vone;
#pragma unroll
  for (int i = 0; i < 8; ++i) vone[i] = (bf)1.0f;

  // stage 64-key tile kt into buffer half `half`: K 8KB + V 8KB, 4 gld16/thread.
  // `half` is a literal at every call site -> dests are loop-invariant.
  auto stage = [&](int half, int kt) {
    bf* Kdst = (bf*)(smem + half * 16384);
    bf* Vdst = (bf*)(smem + half * 16384 + 8192);
#pragma unroll
    for (int p = 0; p < 2; ++p) {
      const int L = p * 256 + tid;      // 512 16B units = 64 rows x 8 units
      const int r = L >> 3, u = L & 7;
      gld16(Kh + (size_t)(kt + r) * HD + ((u ^ (r & 7)) << 3), Kdst + L * 8);
    }
#pragma unroll
    for (int p = 0; p < 2; ++p) {
      const int L = p * 256 + tid;      // 512 units = 64 d-rows x 8 units
      const int d = L >> 3, u = L & 7;
      gld16(Vh + (size_t)d * NT + kt + ((u ^ (d & 7)) << 3), Vdst + L * 8);
    }
  };

  auto computeT = [&](int half) {
    const bf* Kbuf = (const bf*)(smem + half * 16384);
    const bf* Vbuf = (const bf*)(smem + half * 16384 + 8192);
    // S^T = K Q^T on this wave's 32 keys (2 chunks of 16) x its 2 Q sub-tiles.
    // P = exp2(S) goes straight into the v8bf A-fragment (no repack).
    v8bf aP8[2];
#pragma unroll
    for (int e = 0; e < 2; ++e) {
      const int k = kh * 32 + e * 16 + lane15;
      const int k7 = k & 7;
      const v8bf bk0 = *(const v8bf*)(Kbuf + k * 64 + ((quad ^ k7) << 3));
      const v8bf bk1 = *(const v8bf*)(Kbuf + k * 64 + (((quad ^ 4) ^ k7) << 3));
#pragma unroll
      for (int sl = 0; sl < 2; ++sl) {
        v4f z = (v4f){0.f, 0.f, 0.f, 0.f};
        __builtin_amdgcn_s_setprio(1);
        z = __builtin_amdgcn_mfma_f32_16x16x32_bf16(bk0, aQ[sl][0], z, 0, 0, 0);
        z = __builtin_amdgcn_mfma_f32_16x16x32_bf16(bk1, aQ[sl][1], z, 0, 0, 0);
        __builtin_amdgcn_s_setprio(0);
#pragma unroll
        for (int r = 0; r < 4; ++r) aP8[sl][e * 4 + r] = (bf)fexp2(z[r]);
      }
    }
    // denominator via ones-column MFMA, then O += P V on this wave's 32 keys.
#pragma unroll
    for (int sl = 0; sl < 2; ++sl)
      den[sl] = __builtin_amdgcn_mfma_f32_16x16x32_bf16(aP8[sl], vone, den[sl], 0, 0, 0);
#pragma unroll
    for (int dt = 0; dt < 4; ++dt) {
      const int d = dt * 16 + lane15;
      const v8bf bv = *(const v8bf*)(Vbuf + d * 64 + (((kh * 4 + quad) ^ (d & 7)) << 3));
      __builtin_amdgcn_s_setprio(1);
#pragma unroll
      for (int sl = 0; sl < 2; ++sl)
        o[sl][dt] = __builtin_amdgcn_mfma_f32_16x16x32_bf16(aP8[sl], bv, o[sl][dt], 0, 0, 0);
      __builtin_amdgcn_s_setprio(0);
    }
  };

  stage(0, 0);
  asm volatile("s_waitcnt vmcnt(0)" ::: "memory");
  __syncthreads();

#pragma unroll 1
  for (int it2 = 0; it2 < 32; ++it2) {
    const int it = it2 * 2;
    // body A: compute half 0, prefetch tile it+1 into half 1
    stage(1, (it + 1) * 64);
    computeT(0);
    asm volatile("s_waitcnt vmcnt(0)" ::: "memory");
    __syncthreads();
    // body B: compute half 1, prefetch tile it+2 into half 0
    if (it + 2 < 64) stage(0, (it + 2) * 64);
    computeT(1);
    asm volatile("s_waitcnt vmcnt(0)" ::: "memory");
    __syncthreads();
  }

  // cross-wave combine: waves {sh*2, sh*2+1} (kh=0,1) hold key-half partials of the
  // same 2 subs. Two phases (one per local sub); each wave finalizes 2 of the 4 dt.
  float* Red = (float*)smem;             // 4 regions x 1024 f = 16KB
  float* Ls  = (float*)(smem + 16384);   // 64 f
#pragma unroll
  for (int sl = 0; sl < 2; ++sl) {
    __syncthreads();
    float* reg = Red + wave * 1024;
#pragma unroll
    for (int dt = 0; dt < 4; ++dt)
      *(v4f*)(reg + dt * 256 + lane15 * 16 + quad * 4) = o[sl][dt];
    if (lane15 == 0) {
#pragma unroll
      for (int i = 0; i < 4; ++i) Ls[wave * 16 + quad * 4 + i] = den[sl][i];
    }
    __syncthreads();
    const int s = sh * 2 + sl;
    const float dsum = Ls[(sh * 2) * 16 + lane15] + Ls[(sh * 2 + 1) * 16 + lane15];
    const float linv = 1.f / dsum;
#pragma unroll
    for (int dh = 0; dh < 2; ++dh) {
      const int dt = kh * 2 + dh;
      v4f sum = *(const v4f*)(Red + (sh * 2) * 1024 + dt * 256 + lane15 * 16 + quad * 4);
      sum     += *(const v4f*)(Red + (sh * 2 + 1) * 1024 + dt * 256 + lane15 * 16 + quad * 4);
#pragma unroll
      for (int i = 0; i < 4; ++i) {
        const float linv_i = __shfl(linv, quad * 4 + i, 64);
        const int row = q0 + s * 16 + quad * 4 + i;
        Ob[(size_t)row * CD + h * HD + dt * 16 + lane15] = (bf)(sum[i] * linv_i);
      }
    }
  }
}

// ------------- proj GEMM: Ob[4096x768] * WpT[768x768]^T + bias, 64x128 tiles ----------------
__global__ __launch_bounds__(256, 4) void gemm_proj(
    const bf* __restrict__ A, const bf* __restrict__ Bt,
    const float* __restrict__ bias, float* __restrict__ out) {
  __shared__ __align__(16) bf As[2][64 * 32];
  __shared__ __align__(16) bf Bs[2][128 * 32];
  const int tid = threadIdx.x;
  const int lane = tid & 63, wave = tid >> 6;
  const int lane15 = lane & 15, quad = lane >> 4;
  const int bm = blockIdx.x * 64;
  const int bn = blockIdx.y * 128;

  v4f acc[4][2];
#pragma unroll
  for (int i = 0; i < 4; ++i)
#pragma unroll
    for (int j = 0; j < 2; ++j) acc[i][j] = (v4f){0.f, 0.f, 0.f, 0.f};

  auto stageG = [&](int half, int k0) {
    {
      const int r = tid >> 2, c = (tid & 3) * 8;
      gld16(A + (size_t)(bm + r) * CD + k0 + c, As[half] + tid * 8);
    }
#pragma unroll
    for (int p = 0; p < 2; ++p) {
      const int t = tid + p * 256;
      const int r = t >> 2, c = (t & 3) * 8;
      gld16(Bt + (size_t)(bn + r) * CD + k0 + c, Bs[half] + t * 8);
    }
  };

  stageG(0, 0);
  asm volatile("s_waitcnt vmcnt(0)" ::: "memory");
  __syncthreads();

  for (int it = 0; it < CD / 32; ++it) {
    const int half = it & 1;
    if (it + 1 < CD / 32) stageG(half ^ 1, (it + 1) * 32);

    v8bf af[4], bfr[2];
#pragma unroll
    for (int mt = 0; mt < 4; ++mt)
      af[mt] = *(const v8bf*)(As[half] + (mt * 16 + lane15) * 32 + quad * 8);
#pragma unroll
    for (int nt = 0; nt < 2; ++nt)
      bfr[nt] = *(const v8bf*)(Bs[half] + (wave * 32 + nt * 16 + lane15) * 32 + quad * 8);
#pragma unroll
    for (int mt = 0; mt < 4; ++mt)
#pragma unroll
      for (int nt = 0; nt < 2; ++nt)
        acc[mt][nt] = __builtin_amdgcn_mfma_f32_16x16x32_bf16(af[mt], bfr[nt], acc[mt][nt], 0, 0, 0);

    asm volatile("s_waitcnt vmcnt(0)" ::: "memory");
    __syncthreads();
  }

#pragma unroll
  for (int mt = 0; mt < 4; ++mt) {
    const int rowB = bm + mt * 16 + quad * 4;
#pragma unroll
    for (int nt = 0; nt < 2; ++nt) {
      const int col = bn + wave * 32 + nt * 16 + lane15;
      const float bcol = bias[col];
#pragma unroll
      for (int i = 0; i < 4; ++i)
        out[(size_t)(rowB + i) * CD + col] = acc[mt][nt][i] + bcol;
    }
  }
}

extern "C" void kernel_launch(void* const* d_in, const int* in_sizes, int n_in,
                              void* d_out, int out_size, void* d_ws, size_t ws_size,
                              hipStream_t stream) {
  const float* x     = (const float*)d_in[0];   // [4096][768] fp32
  const float* wqkv  = (const float*)d_in[1];   // [768][2304] fp32
  const float* wproj = (const float*)d_in[2];   // [768][768]  fp32
  const float* bproj = (const float*)d_in[3];   // [768]       fp32
  float* out = (float*)d_out;                   // [4096][768] fp32

  bf* ws    = (bf*)d_ws;
  bf* Xb    = ws;  ws += (size_t)NT * CD;        // [4096][768] bf16
  bf* WqkvT = ws;  ws += (size_t)CQ * CD;        // [2304][768]
  bf* WpT   = ws;  ws += (size_t)CD * CD;        // [768][768]
  bf* Qb    = ws;  ws += (size_t)NH * NT * HD;   // [h][n][d], pre-scaled by 0.125*log2e
  bf* Kb    = ws;  ws += (size_t)NH * NT * HD;   // [h][n][d]
  bf* Vtb   = ws;  ws += (size_t)NH * NT * HD;   // [h][d][n], keys PV-slot-permuted per 32
  bf* Ob    = ws;  ws += (size_t)NT * CD;        // [n][h*64+d]

  prep<<<5376, 256, 0, stream>>>(x, wqkv, wproj, Xb, WqkvT, WpT);
  gemm_qkv<<<dim3(NT / 128, CQ / 96), 256, 0, stream>>>(Xb, WqkvT, Qb, Kb, Vtb);
  attn<<<768, 256, 0, stream>>>(Qb, Kb, Vtb, Ob);
  gemm_proj<<<dim3(NT / 64, CD / 128), 256, 0, stream>>>(Ob, WpT, bproj, out);
}

// Round 7
// 159.644 us; speedup vs baseline: 1.3154x; 1.0289x over previous
//
#include <hip/hip_runtime.h>
#include <hip/hip_bf16.h>

#define NT 4096   // tokens
#define CD 768    // channels
#define NH 12     // heads
#define HD 64     // head dim
#define CQ 2304   // 3*CD

typedef __bf16 bf;
typedef __bf16 v8bf __attribute__((ext_vector_type(8)));
typedef __bf16 v4bf __attribute__((ext_vector_type(4)));
typedef float  v4f  __attribute__((ext_vector_type(4)));

// async global->LDS, 16B per lane; LDS dest is wave-uniform base + lane*16
__device__ __forceinline__ void gld16(const bf* g, bf* l) {
  __builtin_amdgcn_global_load_lds(
      (__attribute__((address_space(1))) void*)g,
      (__attribute__((address_space(3))) void*)l,
      16, 0, 0);
}

__device__ __forceinline__ float fexp2(float x) {
#if defined(__HIP_DEVICE_COMPILE__)
  return __builtin_amdgcn_exp2f(x);
#else
  return x;  // host pass never executes device code
#endif
}

// ---------- merged prep: fp32->bf16 cast of x  +  transpose-cast of both weights ----------
__global__ __launch_bounds__(256) void prep(
    const float* __restrict__ x, const float* __restrict__ wqkv,
    const float* __restrict__ wproj, bf* __restrict__ Xb,
    bf* __restrict__ WqkvT, bf* __restrict__ WpT) {
  __shared__ float tile[32][33];
  const int b = blockIdx.x, tid = threadIdx.x;
  if (b < 3072) {
    const int i = b * 256 + tid;  // n4 = 786432 = 3072*256 exactly
    const float4 v = ((const float4*)x)[i];
    bf o4[4] = {(bf)v.x, (bf)v.y, (bf)v.z, (bf)v.w};
    ((ushort4*)Xb)[i] = *(const ushort4*)o4;
    return;
  }
  const float* in;
  bf* out;
  int rows, cols, c0, r0;
  if (b < 4800) {
    const int t = b - 3072;           // 72 col-blocks x 24 row-blocks
    in = wqkv; out = WqkvT; rows = CD; cols = CQ;
    c0 = (t % 72) * 32; r0 = (t / 72) * 32;
  } else {
    const int t = b - 4800;           // 24 x 24
    in = wproj; out = WpT; rows = CD; cols = CD;
    c0 = (t % 24) * 32; r0 = (t / 24) * 32;
  }
  const int tx = tid & 31, ty = tid >> 5;  // 32 x 8
#pragma unroll
  for (int j = 0; j < 32; j += 8)
    tile[ty + j][tx] = in[(size_t)(r0 + ty + j) * cols + (c0 + tx)];
  __syncthreads();
#pragma unroll
  for (int j = 0; j < 32; j += 8)
    out[(size_t)(c0 + ty + j) * rows + (r0 + tx)] = (bf)tile[tx][ty + j];
}

// ------------- QKV GEMM: Xb[4096x768] * WqkvT[2304x768]^T -------------
// 128x96 tiles, grid 32x24 = 768 = exactly 3 blocks/CU; s = by>>3 block-uniform.
// BK=64 single-buffered m97 pattern; XOR swizzle on staging source + fragment reads.
// R7: Q/K epilogue was 48 scalar 2B global stores/thread (row-scattered, stride 128B).
// Now bounced through the (dead) staging LDS: 48 ds_write_b16 -> barrier -> 6 coalesced
// 16B stores/thread. V path (8B PV-permuted stores) unchanged.
__global__ __launch_bounds__(256, 3) void gemm_qkv(
    const bf* __restrict__ A, const bf* __restrict__ Bt,
    bf* __restrict__ Qb, bf* __restrict__ Kb, bf* __restrict__ Vtb) {
  __shared__ __align__(16) bf SMEM[128 * 64 + 96 * 64];  // 28 KB: As | Bs; epilogue Ep[128][96]
  bf* const As = SMEM;
  bf* const Bs = SMEM + 128 * 64;
  const int tid = threadIdx.x;
  const int lane = tid & 63, wave = tid >> 6;
  const int lane15 = lane & 15, quad = lane >> 4;
  const int waveM = wave & 1, waveN = wave >> 1;
  const int bm = blockIdx.x * 128;
  const int by = blockIdx.y;            // 96-col tile index, 0..23
  const int bn = by * 96;

  v4f acc[4][3];
#pragma unroll
  for (int i = 0; i < 4; ++i)
#pragma unroll
    for (int j = 0; j < 3; ++j) acc[i][j] = (v4f){0.f, 0.f, 0.f, 0.f};

  for (int k0 = 0; k0 < CD; k0 += 64) {
    // stage 128x64 A tile (1024 units) and 96x64 B tile (768 units), src-side XOR swizzle
#pragma unroll
    for (int p = 0; p < 4; ++p) {
      const int t = tid + p * 256;
      const int r = t >> 3, u = t & 7;
      gld16(A + (size_t)(bm + r) * CD + k0 + ((u ^ (r & 7)) << 3), As + t * 8);
    }
#pragma unroll
    for (int p = 0; p < 3; ++p) {
      const int t = tid + p * 256;
      const int r = t >> 3, u = t & 7;
      gld16(Bt + (size_t)(bn + r) * CD + k0 + ((u ^ (r & 7)) << 3), Bs + t * 8);
    }
    asm volatile("s_waitcnt vmcnt(0)" ::: "memory");
    __syncthreads();

    v8bf af[4][2], bfr[3][2];
#pragma unroll
    for (int mt = 0; mt < 4; ++mt) {
      const int rr = waveM * 64 + mt * 16 + lane15;
      const int r7 = rr & 7;
      af[mt][0] = *(const v8bf*)(As + rr * 64 + ((quad ^ r7) << 3));
      af[mt][1] = *(const v8bf*)(As + rr * 64 + (((quad ^ 4) ^ r7) << 3));
    }
#pragma unroll
    for (int nt = 0; nt < 3; ++nt) {
      const int rr = waveN * 48 + nt * 16 + lane15;
      const int r7 = rr & 7;
      bfr[nt][0] = *(const v8bf*)(Bs + rr * 64 + ((quad ^ r7) << 3));
      bfr[nt][1] = *(const v8bf*)(Bs + rr * 64 + (((quad ^ 4) ^ r7) << 3));
    }
#pragma unroll
    for (int mt = 0; mt < 4; ++mt)
#pragma unroll
      for (int nt = 0; nt < 3; ++nt) {
        acc[mt][nt] = __builtin_amdgcn_mfma_f32_16x16x32_bf16(af[mt][0], bfr[nt][0], acc[mt][nt], 0, 0, 0);
        acc[mt][nt] = __builtin_amdgcn_mfma_f32_16x16x32_bf16(af[mt][1], bfr[nt][1], acc[mt][nt], 0, 0, 0);
      }
    __syncthreads();
  }

  const float QSCALE = 0.125f * 1.4426950408889634f;  // fold D^-0.5 * log2(e)
  const int s = by >> 3;                // block-uniform: 0=Q 1=K 2=V
  if (s == 2) {
    // V: 4 consecutive keys -> one 8B store at the PV-permuted position (unchanged)
#pragma unroll
    for (int mt = 0; mt < 4; ++mt) {
      const int rowB = bm + waveM * 64 + mt * 16 + quad * 4;
      const int pos = (rowB & ~31) + (((rowB & 15) >> 2) << 3) + (((rowB >> 4) & 1) << 2);
#pragma unroll
      for (int nt = 0; nt < 3; ++nt) {
        const int rem = (by & 7) * 96 + waveN * 48 + nt * 16 + lane15;  // 0..767
        const int h = rem >> 6, d = rem & 63;
        bf vp[4];
#pragma unroll
        for (int i = 0; i < 4; ++i) vp[i] = (bf)acc[mt][nt][i];
        *(uint2*)(Vtb + ((size_t)h * HD + d) * NT + pos) = *(const uint2*)vp;
      }
    }
  } else {
    // Q/K: bounce through LDS (Ep[128][96] aliases staging, dead after final barrier),
    // then 16B coalesced stores. Same rounding as before: (bf)(v*scale) is what lands.
    const float scale = (s == 0) ? QSCALE : 1.0f;
    bf* const Ep = SMEM;
#pragma unroll
    for (int mt = 0; mt < 4; ++mt) {
      const int re = waveM * 64 + mt * 16 + quad * 4;
      const int ce = waveN * 48;
#pragma unroll
      for (int nt = 0; nt < 3; ++nt)
#pragma unroll
        for (int i = 0; i < 4; ++i)
          Ep[(re + i) * 96 + ce + nt * 16 + lane15] = (bf)(acc[mt][nt][i] * scale);
    }
    __syncthreads();
    bf* const base = (s == 0) ? Qb : Kb;
#pragma unroll
    for (int j = 0; j < 6; ++j) {
      const int u = tid + j * 256;          // 1536 = 128 rows x 12 8-col units
      const int row = u / 12, cb = u - row * 12;
      const int gcol = (by & 7) * 96 + cb * 8;
      const int h = gcol >> 6, d = gcol & 63;   // 8-col run never crosses a head (64%8==0)
      *(uint4*)(base + ((size_t)h * NT + bm + row) * HD + d) =
          *(const uint4*)(Ep + row * 96 + cb * 8);
    }
  }
}

// ------------- attention: block = 1 head x 64 Q rows, 256 threads. -------------
// R6 (kept): double-buffered, unrolled x2 with compile-time buffer halves (hoisted LDS
// addrs); den-via-ones-MFMA; direct P pack into A-fragment; setprio; vmcnt(0)+barrier
// per tile (R3 proved the drain is covered by compute: counted-vmcnt removed no stall).
// At 3 waves/SIMD the loop runs ~80% combined issue occupancy (VALU 41 + MFMA 39).
__global__ __launch_bounds__(256, 3) void attn(
    const bf* __restrict__ Qb, const bf* __restrict__ Kb,
    const bf* __restrict__ Vtb, bf* __restrict__ Ob) {
  // [K0 8K][V0 8K][K1 8K][V1 8K]; epilogue reuses 0..16K as 4 x 4KB regions,
  // 16384.. as the denominator scratch.
  __shared__ __align__(16) char smem[32768];

  // head->XCD affinity: blocks of one head land on one XCD (b%8 round-robin heuristic)
  const int b = blockIdx.x;
  int h, qt;
  if (b < 512) { h = b & 7;        qt = b >> 3; }
  else { const int bb = b - 512; h = 8 + (bb & 3); qt = bb >> 2; }
  const int q0 = qt * 64;

  const int tid = threadIdx.x;
  const int wave = tid >> 6, lane = tid & 63;
  const int kh = wave & 1;      // key half (32 keys) of the 64-key tile
  const int sh = wave >> 1;     // Q-subtile half: subs {sh*2, sh*2+1}
  const int lane15 = lane & 15, quad = lane >> 4;

  const bf* Kh = Kb + (size_t)h * NT * HD;
  const bf* Vh = Vtb + (size_t)h * HD * NT;

  // Q fragments for this wave's 2 sub-tiles (B-operand: n=lane15=Q row, k=quad*8+j)
  v8bf aQ[2][2];
#pragma unroll
  for (int sl = 0; sl < 2; ++sl) {
    const int qrow = q0 + (sh * 2 + sl) * 16 + lane15;
    aQ[sl][0] = *(const v8bf*)(Qb + ((size_t)h * NT + qrow) * HD + quad * 8);
    aQ[sl][1] = *(const v8bf*)(Qb + ((size_t)h * NT + qrow) * HD + 32 + quad * 8);
  }

  v4f o[2][4];
#pragma unroll
  for (int sl = 0; sl < 2; ++sl)
#pragma unroll
    for (int dt = 0; dt < 4; ++dt) o[sl][dt] = (v4f){0.f, 0.f, 0.f, 0.f};
  v4f den[2] = {(v4f){0.f, 0.f, 0.f, 0.f}, (v4f){0.f, 0.f, 0.f, 0.f}};
  v8bf vone;
#pragma unroll
  for (int i = 0; i < 8; ++i) vone[i] = (bf)1.0f;

  // stage 64-key tile kt into buffer half `half`: K 8KB + V 8KB, 4 gld16/thread.
  // `half` is a literal at every call site -> dests are loop-invariant.
  auto stage = [&](int half, int kt) {
    bf* Kdst = (bf*)(smem + half * 16384);
    bf* Vdst = (bf*)(smem + half * 16384 + 8192);
#pragma unroll
    for (int p = 0; p < 2; ++p) {
      const int L = p * 256 + tid;      // 512 16B units = 64 rows x 8 units
      const int r = L >> 3, u = L & 7;
      gld16(Kh + (size_t)(kt + r) * HD + ((u ^ (r & 7)) << 3), Kdst + L * 8);
    }
#pragma unroll
    for (int p = 0; p < 2; ++p) {
      const int L = p * 256 + tid;      // 512 units = 64 d-rows x 8 units
      const int d = L >> 3, u = L & 7;
      gld16(Vh + (size_t)d * NT + kt + ((u ^ (d & 7)) << 3), Vdst + L * 8);
    }
  };

  auto computeT = [&](int half) {
    const bf* Kbuf = (const bf*)(smem + half * 16384);
    const bf* Vbuf = (const bf*)(smem + half * 16384 + 8192);
    // S^T = K Q^T on this wave's 32 keys (2 chunks of 16) x its 2 Q sub-tiles.
    // P = exp2(S) goes straight into the v8bf A-fragment (no repack).
    v8bf aP8[2];
#pragma unroll
    for (int e = 0; e < 2; ++e) {
      const int k = kh * 32 + e * 16 + lane15;
      const int k7 = k & 7;
      const v8bf bk0 = *(const v8bf*)(Kbuf + k * 64 + ((quad ^ k7) << 3));
      const v8bf bk1 = *(const v8bf*)(Kbuf + k * 64 + (((quad ^ 4) ^ k7) << 3));
#pragma unroll
      for (int sl = 0; sl < 2; ++sl) {
        v4f z = (v4f){0.f, 0.f, 0.f, 0.f};
        __builtin_amdgcn_s_setprio(1);
        z = __builtin_amdgcn_mfma_f32_16x16x32_bf16(bk0, aQ[sl][0], z, 0, 0, 0);
        z = __builtin_amdgcn_mfma_f32_16x16x32_bf16(bk1, aQ[sl][1], z, 0, 0, 0);
        __builtin_amdgcn_s_setprio(0);
#pragma unroll
        for (int r = 0; r < 4; ++r) aP8[sl][e * 4 + r] = (bf)fexp2(z[r]);
      }
    }
    // denominator via ones-column MFMA, then O += P V on this wave's 32 keys.
#pragma unroll
    for (int sl = 0; sl < 2; ++sl)
      den[sl] = __builtin_amdgcn_mfma_f32_16x16x32_bf16(aP8[sl], vone, den[sl], 0, 0, 0);
#pragma unroll
    for (int dt = 0; dt < 4; ++dt) {
      const int d = dt * 16 + lane15;
      const v8bf bv = *(const v8bf*)(Vbuf + d * 64 + (((kh * 4 + quad) ^ (d & 7)) << 3));
      __builtin_amdgcn_s_setprio(1);
#pragma unroll
      for (int sl = 0; sl < 2; ++sl)
        o[sl][dt] = __builtin_amdgcn_mfma_f32_16x16x32_bf16(aP8[sl], bv, o[sl][dt], 0, 0, 0);
      __builtin_amdgcn_s_setprio(0);
    }
  };

  stage(0, 0);
  asm volatile("s_waitcnt vmcnt(0)" ::: "memory");
  __syncthreads();

#pragma unroll 1
  for (int it2 = 0; it2 < 32; ++it2) {
    const int it = it2 * 2;
    // body A: compute half 0, prefetch tile it+1 into half 1
    stage(1, (it + 1) * 64);
    computeT(0);
    asm volatile("s_waitcnt vmcnt(0)" ::: "memory");
    __syncthreads();
    // body B: compute half 1, prefetch tile it+2 into half 0
    if (it + 2 < 64) stage(0, (it + 2) * 64);
    computeT(1);
    asm volatile("s_waitcnt vmcnt(0)" ::: "memory");
    __syncthreads();
  }

  // cross-wave combine: waves {sh*2, sh*2+1} (kh=0,1) hold key-half partials of the
  // same 2 subs. Two phases (one per local sub); each wave finalizes 2 of the 4 dt.
  float* Red = (float*)smem;             // 4 regions x 1024 f = 16KB
  float* Ls  = (float*)(smem + 16384);   // 64 f
#pragma unroll
  for (int sl = 0; sl < 2; ++sl) {
    __syncthreads();
    float* reg = Red + wave * 1024;
#pragma unroll
    for (int dt = 0; dt < 4; ++dt)
      *(v4f*)(reg + dt * 256 + lane15 * 16 + quad * 4) = o[sl][dt];
    if (lane15 == 0) {
#pragma unroll
      for (int i = 0; i < 4; ++i) Ls[wave * 16 + quad * 4 + i] = den[sl][i];
    }
    __syncthreads();
    const int s = sh * 2 + sl;
    const float dsum = Ls[(sh * 2) * 16 + lane15] + Ls[(sh * 2 + 1) * 16 + lane15];
    const float linv = 1.f / dsum;
#pragma unroll
    for (int dh = 0; dh < 2; ++dh) {
      const int dt = kh * 2 + dh;
      v4f sum = *(const v4f*)(Red + (sh * 2) * 1024 + dt * 256 + lane15 * 16 + quad * 4);
      sum     += *(const v4f*)(Red + (sh * 2 + 1) * 1024 + dt * 256 + lane15 * 16 + quad * 4);
#pragma unroll
      for (int i = 0; i < 4; ++i) {
        const float linv_i = __shfl(linv, quad * 4 + i, 64);
        const int row = q0 + s * 16 + quad * 4 + i;
        Ob[(size_t)row * CD + h * HD + dt * 16 + lane15] = (bf)(sum[i] * linv_i);
      }
    }
  }
}

// ------------- proj GEMM: Ob[4096x768] * WpT[768x768]^T + bias ----------------
// R7: 64x96 tiles (was 64x128): grid 64x8 = 512 blocks = exactly 2 blocks/CU (was
// 384 = 1.5/CU -> ~33% idle on the second round). BK 32->64 and the qkv XOR-swizzle
// pattern (old stride-64B fragment reads were ~8-way bank-conflicted).
__global__ __launch_bounds__(256, 2) void gemm_proj(
    const bf* __restrict__ A, const bf* __restrict__ Bt,
    const float* __restrict__ bias, float* __restrict__ out) {
  __shared__ __align__(16) bf As[64 * 64];   // 8 KB
  __shared__ __align__(16) bf Bs[96 * 64];   // 12 KB
  const int tid = threadIdx.x;
  const int lane = tid & 63, wave = tid >> 6;
  const int lane15 = lane & 15, quad = lane >> 4;
  const int waveM = wave & 1, waveN = wave >> 1;
  const int bm = blockIdx.x * 64;
  const int bn = blockIdx.y * 96;

  v4f acc[2][3];
#pragma unroll
  for (int i = 0; i < 2; ++i)
#pragma unroll
    for (int j = 0; j < 3; ++j) acc[i][j] = (v4f){0.f, 0.f, 0.f, 0.f};

  for (int k0 = 0; k0 < CD; k0 += 64) {
    // stage 64x64 A (512 units) + 96x64 B (768 units), src-side XOR swizzle
#pragma unroll
    for (int p = 0; p < 2; ++p) {
      const int t = tid + p * 256;
      const int r = t >> 3, u = t & 7;
      gld16(A + (size_t)(bm + r) * CD + k0 + ((u ^ (r & 7)) << 3), As + t * 8);
    }
#pragma unroll
    for (int p = 0; p < 3; ++p) {
      const int t = tid + p * 256;
      const int r = t >> 3, u = t & 7;
      gld16(Bt + (size_t)(bn + r) * CD + k0 + ((u ^ (r & 7)) << 3), Bs + t * 8);
    }
    asm volatile("s_waitcnt vmcnt(0)" ::: "memory");
    __syncthreads();

    v8bf af[2][2], bfr[3][2];
#pragma unroll
    for (int mt = 0; mt < 2; ++mt) {
      const int rr = waveM * 32 + mt * 16 + lane15;
      const int r7 = rr & 7;
      af[mt][0] = *(const v8bf*)(As + rr * 64 + ((quad ^ r7) << 3));
      af[mt][1] = *(const v8bf*)(As + rr * 64 + (((quad ^ 4) ^ r7) << 3));
    }
#pragma unroll
    for (int nt = 0; nt < 3; ++nt) {
      const int rr = waveN * 48 + nt * 16 + lane15;
      const int r7 = rr & 7;
      bfr[nt][0] = *(const v8bf*)(Bs + rr * 64 + ((quad ^ r7) << 3));
      bfr[nt][1] = *(const v8bf*)(Bs + rr * 64 + (((quad ^ 4) ^ r7) << 3));
    }
#pragma unroll
    for (int mt = 0; mt < 2; ++mt)
#pragma unroll
      for (int nt = 0; nt < 3; ++nt) {
        acc[mt][nt] = __builtin_amdgcn_mfma_f32_16x16x32_bf16(af[mt][0], bfr[nt][0], acc[mt][nt], 0, 0, 0);
        acc[mt][nt] = __builtin_amdgcn_mfma_f32_16x16x32_bf16(af[mt][1], bfr[nt][1], acc[mt][nt], 0, 0, 0);
      }
    __syncthreads();
  }

#pragma unroll
  for (int mt = 0; mt < 2; ++mt) {
    const int rowB = bm + waveM * 32 + mt * 16 + quad * 4;
#pragma unroll
    for (int nt = 0; nt < 3; ++nt) {
      const int col = bn + waveN * 48 + nt * 16 + lane15;
      const float bcol = bias[col];
#pragma unroll
      for (int i = 0; i < 4; ++i)
        out[(size_t)(rowB + i) * CD + col] = acc[mt][nt][i] + bcol;
    }
  }
}

extern "C" void kernel_launch(void* const* d_in, const int* in_sizes, int n_in,
                              void* d_out, int out_size, void* d_ws, size_t ws_size,
                              hipStream_t stream) {
  const float* x     = (const float*)d_in[0];   // [4096][768] fp32
  const float* wqkv  = (const float*)d_in[1];   // [768][2304] fp32
  const float* wproj = (const float*)d_in[2];   // [768][768]  fp32
  const float* bproj = (const float*)d_in[3];   // [768]       fp32
  float* out = (float*)d_out;                   // [4096][768] fp32

  bf* ws    = (bf*)d_ws;
  bf* Xb    = ws;  ws += (size_t)NT * CD;        // [4096][768] bf16
  bf* WqkvT = ws;  ws += (size_t)CQ * CD;        // [2304][768]
  bf* WpT   = ws;  ws += (size_t)CD * CD;        // [768][768]
  bf* Qb    = ws;  ws += (size_t)NH * NT * HD;   // [h][n][d], pre-scaled by 0.125*log2e
  bf* Kb    = ws;  ws += (size_t)NH * NT * HD;   // [h][n][d]
  bf* Vtb   = ws;  ws += (size_t)NH * NT * HD;   // [h][d][n], keys PV-slot-permuted per 32
  bf* Ob    = ws;  ws += (size_t)NT * CD;        // [n][h*64+d]

  prep<<<5376, 256, 0, stream>>>(x, wqkv, wproj, Xb, WqkvT, WpT);
  gemm_qkv<<<dim3(NT / 128, CQ / 96), 256, 0, stream>>>(Xb, WqkvT, Qb, Kb, Vtb);
  attn<<<768, 256, 0, stream>>>(Qb, Kb, Vtb, Ob);
  gemm_proj<<<dim3(NT / 64, CD / 96), 256, 0, stream>>>(Ob, WpT, bproj, out);
}